// Round 7
// baseline (422.475 us; speedup 1.0000x reference)
//
#include <hip/hip_runtime.h>
#include <hip/hip_bf16.h>
#include <math.h>

#define T_SNAP 4
#define EQn 4096
#define Nn 8192
#define Hn 32
#define NWn (Nn/32)   // 256 bitset words per reach set
#define CAP 256       // reach-list capacity (E[|R|] ~ 2.3)
#define NBLK 4096     // mega grid size (one block per 4 (t,q) waves)
#define GRU_BLKS 192  // blocks that run the GRU tail (192*4 waves*16 rows = 12288)

typedef __attribute__((ext_vector_type(4))) float f32x4;
typedef __attribute__((ext_vector_type(8))) short s16x8;

__device__ __forceinline__ short f2bfs(float x) {
  __hip_bfloat16 h = __float2bfloat16(x);
  short s;
  __builtin_memcpy(&s, &h, 2);
  return s;
}
__device__ __forceinline__ float sigm(float x) {
  return __builtin_amdgcn_rcpf(1.f + __expf(-x));
}
__device__ __forceinline__ float tanhfast(float x) {
  return 1.f - 2.f * __builtin_amdgcn_rcpf(1.f + __expf(2.f * x));
}
// wave-internal LDS ordering fence (no inter-wave coupling)
__device__ __forceinline__ void tfb() { __threadfence_block(); }

// ---------------------------------------------------------------------------
// Kernel 1: per-snapshot CSR by dst. Edge list stashed in LDS during the
// count pass so the fill pass avoids a second cold-HBM read. Also zeroes the
// device semaphore for kernel 2 (stream order guarantees visibility).
// ---------------------------------------------------------------------------
__global__ __launch_bounds__(1024) void csr_build(const int* __restrict__ ei,
                                                  unsigned* __restrict__ rp,
                                                  unsigned* __restrict__ csr,
                                                  unsigned* __restrict__ sem) {
  __shared__ unsigned cnt[Nn];                 // 32KB
  __shared__ unsigned short sst[EQn], sdt[EQn];// 16KB
  __shared__ unsigned wpart[16];
  const int t = blockIdx.x;
  const int tid = threadIdx.x;
  const int lane = tid & 63;
  const int wv = tid >> 6;
  const int* src = ei + t * 2 * EQn;
  const int* dst = src + EQn;

  if (t == 0 && tid == 0) *sem = 0u;

  for (int i = tid; i < Nn; i += 1024) cnt[i] = 0u;
  __syncthreads();
  for (int e = tid; e < EQn; e += 1024) {
    const int s_ = src[e], d_ = dst[e];
    sst[e] = (unsigned short)s_;
    sdt[e] = (unsigned short)d_;
    atomicAdd(&cnt[d_], 1u);
  }
  __syncthreads();

  // per-thread sum of 8 contiguous counts, wave scan, 16-partial scan
  unsigned loc[8];
  unsigned s = 0u;
  const int base = tid * 8;
#pragma unroll
  for (int i = 0; i < 8; i++) { loc[i] = s; s += cnt[base + i]; }
  unsigned x = s;
#pragma unroll
  for (int off = 1; off < 64; off <<= 1) {
    unsigned y = __shfl_up(x, off);
    if (lane >= off) x += y;
  }
  if (lane == 63) wpart[wv] = x;
  __syncthreads();
  if (tid == 0) {
    unsigned a = 0u;
#pragma unroll
    for (int i = 0; i < 16; i++) { unsigned v = wpart[i]; wpart[i] = a; a += v; }
  }
  __syncthreads();
  const unsigned excl = wpart[wv] + (x - s);
#pragma unroll
  for (int i = 0; i < 8; i++) {
    unsigned v = excl + loc[i];
    rp[t * (Nn + 1) + base + i] = v;
    cnt[base + i] = v;  // running fill cursors
  }
  if (tid == 0) rp[t * (Nn + 1) + Nn] = EQn;
  __syncthreads();

  for (int e = tid; e < EQn; e += 1024) {
    const unsigned d = sdt[e];
    unsigned slot = atomicAdd(&cnt[d], 1u);
    csr[t * EQn + slot] = (unsigned)sst[e];
  }
}

// ---------------------------------------------------------------------------
// Kernel 2: mega. All blocks: reach+top3 for gw=blockIdx*4+w (r6-verified
// body, wave-private LDS, no __syncthreads in the BFS). Then fence + sem++.
// Blocks 0..191: prep GRU weight frags (overlaps spin), spin until sem==NBLK,
// acquire fence, run r6-verified fused GCN+GRU on rows gw*16..gw*16+15.
// ---------------------------------------------------------------------------
__global__ __launch_bounds__(256, 4) void mega(
    const int* __restrict__ ei, const unsigned* __restrict__ rp,
    const unsigned* __restrict__ csr, float* __restrict__ tops,
    unsigned* __restrict__ sem,
    const float* __restrict__ Wg, const float* __restrict__ bg,
    const float* __restrict__ Wih, const float* __restrict__ Whh,
    const float* __restrict__ bih, const float* __restrict__ bhh,
    float* __restrict__ out) {
  __shared__ unsigned bits[4][2][NWn];          // 8KB (reused as hbuf in GRU)
  __shared__ unsigned short lists[4][2][CAP];   // 4KB
  __shared__ unsigned cnts[4][2];

  const int w = threadIdx.x >> 6;
  const int lane = threadIdx.x & 63;
  const int h = lane >> 5;       // 0: U-half, 1: V-half
  const int l = lane & 31;
  const int gw = blockIdx.x * 4 + w;
  const int t = gw >> 12;        // EQn = 4096 = 2^12
  const int q = gw & (EQn - 1);

  // ---------------- reach + top-3 ----------------
  {
    unsigned* bset = bits[w][h];
    unsigned short* lst = lists[w][h];
    const unsigned* rpt = rp + t * (Nn + 1);
    const unsigned* ct = csr + t * EQn;

    const unsigned seed = (unsigned)ei[(T_SNAP - 1) * 2 * EQn + h * EQn + q];
    const unsigned sb0 = rpt[seed];
    const unsigned sb1 = rpt[seed + 1];

    for (int i = l; i < NWn; i += 32) bset[i] = 0u;
    tfb();
    if (l == 0) {
      bset[seed >> 5] = 1u << (seed & 31);
      lst[0] = (unsigned short)seed;
      cnts[w][h] = 1u;
    }
    tfb();
    // hop 0
    for (unsigned idx = sb0 + l; idx < sb1; idx += 32) {
      const unsigned sN = ct[idx];
      const unsigned m = 1u << (sN & 31);
      const unsigned old = atomicOr(&bset[sN >> 5], m);
      if (!(old & m)) {
        unsigned pos = atomicAdd(&cnts[w][h], 1u);
        if (pos < CAP) lst[pos] = (unsigned short)sN;
      }
    }
    tfb();
    // hop 1
    {
      const unsigned fe = min(cnts[w][h], (unsigned)CAP);
      for (unsigned i = 1 + l; i < fe; i += 32) {
        const unsigned n = lst[i];
        const unsigned b0 = rpt[n], b1 = rpt[n + 1];
        for (unsigned idx = b0; idx < b1; idx++) {
          const unsigned sN = ct[idx];
          const unsigned m = 1u << (sN & 31);
          const unsigned old = atomicOr(&bset[sN >> 5], m);
          if (!(old & m)) {
            unsigned pos = atomicAdd(&cnts[w][h], 1u);
            if (pos < CAP) lst[pos] = (unsigned short)sN;
          }
        }
      }
    }
    tfb();
    // merged-subgraph in-degree + per-lane top-3
    const unsigned* bu = bits[w][0];
    const unsigned* bv = bits[w][1];
    const unsigned cn = min(cnts[w][h], (unsigned)CAP);
    int a0 = 0, a1 = 0, a2 = 0;
    for (unsigned i = l; i < cn; i += 32) {
      const unsigned n = lst[i];
      if (h == 1 && ((bu[n >> 5] >> (n & 31)) & 1u)) continue;
      const bool nv = (bv[n >> 5] >> (n & 31)) & 1u;
      const unsigned b0 = rpt[n], b1 = rpt[n + 1];
      int d = 0;
      for (unsigned idx = b0; idx < b1; idx++) {
        const unsigned sN = ct[idx];
        if (h == 0) {
          const bool su = (bu[sN >> 5] >> (sN & 31)) & 1u;
          const bool sv = (bv[sN >> 5] >> (sN & 31)) & 1u;
          d += (su || (nv && sv)) ? 1 : 0;
        } else {
          d += (bv[sN >> 5] >> (sN & 31)) & 1u;
        }
      }
      a2 = max(a2, min(a1, d)); a1 = max(a1, min(a0, d)); a0 = max(a0, d);
    }
#pragma unroll
    for (int m = 1; m < 64; m <<= 1) {
      const int b0 = __shfl_xor(a0, m);
      const int b1 = __shfl_xor(a1, m);
      const int b2 = __shfl_xor(a2, m);
      const int r0 = max(a0, b0);
      const int r1 = max(min(a0, b0), max(a1, b1));
      const int r2 = max(max(a2, b2), max(min(a1, b0), min(a0, b1)));
      a0 = r0; a1 = r1; a2 = r2;
    }
    if (lane == 0) {
      float* o = tops + (size_t)(t * EQn + q) * 3;
      o[0] = (float)a0;
      o[1] = (float)a1;
      o[2] = (float)a2;
    }
  }
  __syncthreads();
  if (threadIdx.x == 0) {
    __threadfence();          // release: write back L2 (tops -> IF$)
    atomicAdd(sem, 1u);       // device-scope
  }
  if (blockIdx.x >= GRU_BLKS) return;

  // ---------------- GRU weight prep (overlaps semaphore wait) ----------------
  const int quad = lane >> 4;
  const int c = lane & 15;
  const int rowbase = gw * 16;

  const f32x4* Wih4 = reinterpret_cast<const f32x4*>(Wih);
  const f32x4* Whh4 = reinterpret_cast<const f32x4*>(Whh);
  s16x8 Bih[6], Bhh[6];
#pragma unroll
  for (int g = 0; g < 6; g++) {
    const int row = g * 16 + c;
    const int v4 = row * (Hn / 4) + quad * 2;
    f32x4 wa = Wih4[v4], wb = Wih4[v4 + 1];
    f32x4 ha = Whh4[v4], hb = Whh4[v4 + 1];
#pragma unroll
    for (int j = 0; j < 4; j++) {
      Bih[g][j] = f2bfs(wa[j]);
      Bih[g][j + 4] = f2bfs(wb[j]);
      Bhh[g][j] = f2bfs(ha[j]);
      Bhh[g][j + 4] = f2bfs(hb[j]);
    }
  }
  const f32x4* Wg4 = reinterpret_cast<const f32x4*>(Wg);
  const f32x4* bg4 = reinterpret_cast<const f32x4*>(bg);
  f32x4 wga = Wg4[quad * 2], wgb = Wg4[quad * 2 + 1];
  f32x4 bga = bg4[quad * 2], bgb = bg4[quad * 2 + 1];
  float wgv[8], bgv[8];
#pragma unroll
  for (int j = 0; j < 4; j++) {
    wgv[j] = wga[j]; wgv[j + 4] = wgb[j];
    bgv[j] = bga[j]; bgv[j + 4] = bgb[j];
  }
  float bihv[6], bhhv[6];
#pragma unroll
  for (int g = 0; g < 6; g++) {
    bihv[g] = bih[g * 16 + c];
    bhhv[g] = bhh[g * 16 + c];
  }

  // ---------------- wait for all tops ----------------
  if (threadIdx.x == 0) {
    while (__hip_atomic_load(sem, __ATOMIC_RELAXED, __HIP_MEMORY_SCOPE_AGENT)
           < (unsigned)NBLK)
      __builtin_amdgcn_s_sleep(16);
  }
  __syncthreads();
  __threadfence();            // acquire: invalidate L2, read tops from IF$

  // ---------------- fused GCN + 4-step GRU ----------------
  short* hbuf = (short*)&bits[w][0][0];  // 1KB per wave, bits region is dead
  f32x4 hc0 = {0.f, 0.f, 0.f, 0.f};
  f32x4 hc1 = {0.f, 0.f, 0.f, 0.f};
  s16x8 hfrag = {0, 0, 0, 0, 0, 0, 0, 0};
  const f32x4 z4 = {0.f, 0.f, 0.f, 0.f};

  for (int tt = 0; tt < T_SNAP; tt++) {
    const float top = tops[tt * (EQn * 3) + rowbase + c];
    s16x8 xf;
#pragma unroll
    for (int j = 0; j < 8; j++) {
      float x = top * wgv[j] + bgv[j];
      x = x > 0.f ? x : 0.f;
      xf[j] = f2bfs(x);
    }
    f32x4 gi[6], gh[6];
#pragma unroll
    for (int g = 0; g < 6; g++) {
      gi[g] = __builtin_amdgcn_mfma_f32_16x16x32_bf16(xf, Bih[g], z4, 0, 0, 0);
      gh[g] = __builtin_amdgcn_mfma_f32_16x16x32_bf16(hfrag, Bhh[g], z4, 0, 0, 0);
    }
#pragma unroll
    for (int r = 0; r < 4; r++) {
      float rA = sigm(gi[0][r] + bihv[0] + gh[0][r] + bhhv[0]);
      float zA = sigm(gi[2][r] + bihv[2] + gh[2][r] + bhhv[2]);
      float nA = tanhfast(gi[4][r] + bihv[4] + rA * (gh[4][r] + bhhv[4]));
      hc0[r] = (1.f - zA) * nA + zA * hc0[r];
      float rB = sigm(gi[1][r] + bihv[1] + gh[1][r] + bhhv[1]);
      float zB = sigm(gi[3][r] + bihv[3] + gh[3][r] + bhhv[3]);
      float nB = tanhfast(gi[5][r] + bihv[5] + rB * (gh[5][r] + bhhv[5]));
      hc1[r] = (1.f - zB) * nB + zB * hc1[r];
    }
    if (tt < T_SNAP - 1) {
      tfb();
#pragma unroll
      for (int r = 0; r < 4; r++) {
        const int row = quad * 4 + r;
        hbuf[row * Hn + c] = f2bfs(hc0[r]);
        hbuf[row * Hn + 16 + c] = f2bfs(hc1[r]);
      }
      tfb();
      hfrag = *reinterpret_cast<const s16x8*>(&hbuf[c * Hn + quad * 8]);
    }
  }
#pragma unroll
  for (int r = 0; r < 4; r++) {
    const int grow = rowbase + quad * 4 + r;
    out[grow * Hn + c] = hc0[r];
    out[grow * Hn + 16 + c] = hc1[r];
  }
}

// ---------------------------------------------------------------------------
extern "C" void kernel_launch(void* const* d_in, const int* in_sizes, int n_in,
                              void* d_out, int out_size, void* d_ws, size_t ws_size,
                              hipStream_t stream) {
  const int* ei = (const int*)d_in[0];
  const float* Wg = (const float*)d_in[1];
  const float* bg = (const float*)d_in[2];
  const float* Wih = (const float*)d_in[3];
  const float* Whh = (const float*)d_in[4];
  const float* bih = (const float*)d_in[5];
  const float* bhh = (const float*)d_in[6];

  unsigned char* ws = (unsigned char*)d_ws;
  unsigned* rp = (unsigned*)ws;                                      // [T][N+1] u32
  unsigned* csr = (unsigned*)(ws + (size_t)T_SNAP * (Nn + 1) * 4);   // [T][EQ]  u32
  float* tops = (float*)(ws + (size_t)T_SNAP * (Nn + 1) * 4
                            + (size_t)T_SNAP * EQn * 4);             // [T][EQ*3] f32
  unsigned* sem = (unsigned*)(ws + (size_t)T_SNAP * (Nn + 1) * 4
                                 + (size_t)T_SNAP * EQn * 4
                                 + (size_t)T_SNAP * EQn * 3 * 4);    // 1 u32

  csr_build<<<T_SNAP, 1024, 0, stream>>>(ei, rp, csr, sem);
  mega<<<NBLK, 256, 0, stream>>>(ei, rp, csr, tops, sem, Wg, bg, Wih, Whh,
                                 bih, bhh, (float*)d_out);
}

// Round 8
// 90.211 us; speedup vs baseline: 4.6832x; 4.6832x over previous
//
#include <hip/hip_runtime.h>
#include <hip/hip_bf16.h>
#include <math.h>

#define T_SNAP 4
#define EQn 4096
#define Nn 8192
#define Hn 32
#define NWn (Nn/32)   // 256 bitset words per reach set
#define CAP 256       // reach-list capacity (E[|R|] ~ 2.3)

typedef __attribute__((ext_vector_type(4))) float f32x4;
typedef __attribute__((ext_vector_type(8))) short s16x8;

__device__ __forceinline__ short f2bfs(float x) {
  __hip_bfloat16 h = __float2bfloat16(x);
  short s;
  __builtin_memcpy(&s, &h, 2);
  return s;
}
__device__ __forceinline__ float sigm(float x) {
  return __builtin_amdgcn_rcpf(1.f + __expf(-x));
}
__device__ __forceinline__ float tanhfast(float x) {
  return 1.f - 2.f * __builtin_amdgcn_rcpf(1.f + __expf(2.f * x));
}
// wave-internal LDS ordering fence (no inter-wave coupling)
__device__ __forceinline__ void tfb() { __threadfence_block(); }

// ---------------------------------------------------------------------------
// Kernel 1: per-snapshot CSR by dst. 1024 threads (16 waves) per block for
// latency hiding on this 4-CU phase. (r6-verified)
// ---------------------------------------------------------------------------
__global__ __launch_bounds__(1024) void csr_build(const int* __restrict__ ei,
                                                  unsigned* __restrict__ rp,
                                                  unsigned* __restrict__ csr) {
  __shared__ unsigned cnt[Nn];
  __shared__ unsigned wpart[16];
  const int t = blockIdx.x;
  const int tid = threadIdx.x;
  const int lane = tid & 63;
  const int wv = tid >> 6;
  const int* src = ei + t * 2 * EQn;
  const int* dst = src + EQn;

  for (int i = tid; i < Nn; i += 1024) cnt[i] = 0u;
  __syncthreads();
  for (int e = tid; e < EQn; e += 1024) atomicAdd(&cnt[dst[e]], 1u);
  __syncthreads();

  // per-thread sum of 8 contiguous counts
  unsigned loc[8];
  unsigned s = 0u;
  const int base = tid * 8;
#pragma unroll
  for (int i = 0; i < 8; i++) { loc[i] = s; s += cnt[base + i]; }
  unsigned x = s;
#pragma unroll
  for (int off = 1; off < 64; off <<= 1) {
    unsigned y = __shfl_up(x, off);
    if (lane >= off) x += y;
  }
  if (lane == 63) wpart[wv] = x;
  __syncthreads();
  if (tid == 0) {
    unsigned a = 0u;
#pragma unroll
    for (int i = 0; i < 16; i++) { unsigned v = wpart[i]; wpart[i] = a; a += v; }
  }
  __syncthreads();
  const unsigned excl = wpart[wv] + (x - s);
#pragma unroll
  for (int i = 0; i < 8; i++) {
    unsigned v = excl + loc[i];
    rp[t * (Nn + 1) + base + i] = v;
    cnt[base + i] = v;  // running fill cursors
  }
  if (tid == 0) rp[t * (Nn + 1) + Nn] = EQn;
  __syncthreads();

  for (int e = tid; e < EQn; e += 1024) {
    int d = dst[e];
    unsigned slot = atomicAdd(&cnt[d], 1u);
    csr[t * EQn + slot] = (unsigned)src[e];
  }
}

// ---------------------------------------------------------------------------
// Kernel 2: one wave per (t,q); lanes 0-31 build the U reach set, lanes 32-63
// build V concurrently. NO __syncthreads — all state wave-private. Seed rp
// loads hoisted before bitset zeroing to overlap VMEM latency. (r6-verified)
// ---------------------------------------------------------------------------
__global__ __launch_bounds__(256) void reach_topk(const int* __restrict__ ei,
                                                  const unsigned* __restrict__ rp,
                                                  const unsigned* __restrict__ csr,
                                                  float* __restrict__ tops) {
  __shared__ unsigned bits[4][2][NWn];          // 8KB
  __shared__ unsigned short lists[4][2][CAP];   // 4KB
  __shared__ unsigned cnts[4][2];

  const int w = threadIdx.x >> 6;
  const int lane = threadIdx.x & 63;
  const int h = lane >> 5;       // 0: U-half, 1: V-half
  const int l = lane & 31;
  const int gw = blockIdx.x * 4 + w;
  const int t = gw >> 12;        // EQn = 4096 = 2^12
  const int q = gw & (EQn - 1);

  unsigned* bset = bits[w][h];
  unsigned short* lst = lists[w][h];

  const unsigned* rpt = rp + t * (Nn + 1);
  const unsigned* ct = csr + t * EQn;

  // issue the dependent-load chain head ASAP (overlaps with LDS zeroing)
  const unsigned seed = (unsigned)ei[(T_SNAP - 1) * 2 * EQn + h * EQn + q];
  const unsigned sb0 = rpt[seed];
  const unsigned sb1 = rpt[seed + 1];

  for (int i = l; i < NWn; i += 32) bset[i] = 0u;
  tfb();
  if (l == 0) {
    bset[seed >> 5] = 1u << (seed & 31);
    lst[0] = (unsigned short)seed;
    cnts[w][h] = 1u;
  }
  tfb();

  // hop 0: seed's in-edges, edge-parallel over this half's 32 lanes
  for (unsigned idx = sb0 + l; idx < sb1; idx += 32) {
    const unsigned sN = ct[idx];
    const unsigned m = 1u << (sN & 31);
    const unsigned old = atomicOr(&bset[sN >> 5], m);
    if (!(old & m)) {
      unsigned pos = atomicAdd(&cnts[w][h], 1u);
      if (pos < CAP) lst[pos] = (unsigned short)sN;
    }
  }
  tfb();

  // hop 1: frontier = nodes appended in hop 0
  {
    const unsigned fe = min(cnts[w][h], (unsigned)CAP);
    for (unsigned i = 1 + l; i < fe; i += 32) {
      const unsigned n = lst[i];
      const unsigned b0 = rpt[n], b1 = rpt[n + 1];
      for (unsigned idx = b0; idx < b1; idx++) {
        const unsigned sN = ct[idx];
        const unsigned m = 1u << (sN & 31);
        const unsigned old = atomicOr(&bset[sN >> 5], m);
        if (!(old & m)) {
          unsigned pos = atomicAdd(&cnts[w][h], 1u);
          if (pos < CAP) lst[pos] = (unsigned short)sN;
        }
      }
    }
  }
  tfb();

  // merged-subgraph in-degree + per-lane top-3
  const unsigned* bu = bits[w][0];
  const unsigned* bv = bits[w][1];
  const unsigned cn = min(cnts[w][h], (unsigned)CAP);
  int a0 = 0, a1 = 0, a2 = 0;
  for (unsigned i = l; i < cn; i += 32) {
    const unsigned n = lst[i];
    if (h == 1 && ((bu[n >> 5] >> (n & 31)) & 1u)) continue;
    const bool nv = (bv[n >> 5] >> (n & 31)) & 1u;
    const unsigned b0 = rpt[n], b1 = rpt[n + 1];
    int d = 0;
    for (unsigned idx = b0; idx < b1; idx++) {
      const unsigned sN = ct[idx];
      if (h == 0) {
        const bool su = (bu[sN >> 5] >> (sN & 31)) & 1u;
        const bool sv = (bv[sN >> 5] >> (sN & 31)) & 1u;
        d += (su || (nv && sv)) ? 1 : 0;
      } else {
        d += (bv[sN >> 5] >> (sN & 31)) & 1u;
      }
    }
    a2 = max(a2, min(a1, d)); a1 = max(a1, min(a0, d)); a0 = max(a0, d);
  }

  // 64-lane butterfly merge of sorted triples (merges U and V halves too)
#pragma unroll
  for (int m = 1; m < 64; m <<= 1) {
    const int b0 = __shfl_xor(a0, m);
    const int b1 = __shfl_xor(a1, m);
    const int b2 = __shfl_xor(a2, m);
    const int r0 = max(a0, b0);
    const int r1 = max(min(a0, b0), max(a1, b1));
    const int r2 = max(max(a2, b2), max(min(a1, b0), min(a0, b1)));
    a0 = r0; a1 = r1; a2 = r2;
  }
  if (lane == 0) {
    float* o = tops + (size_t)(t * EQn + q) * 3;
    o[0] = (float)a0;
    o[1] = (float)a1;
    o[2] = (float)a2;
  }
}

// ---------------------------------------------------------------------------
// Kernel 3: fused GCN + 4-step GRU via mfma_f32_16x16x32_bf16 (r6-verified
// body). 256 blocks x 192 threads (3 waves): one block per CU, all 256 CUs.
// ---------------------------------------------------------------------------
__global__ __launch_bounds__(192) void gru_kernel(
    const float* __restrict__ tops,
    const float* __restrict__ Wg, const float* __restrict__ bg,
    const float* __restrict__ Wih, const float* __restrict__ Whh,
    const float* __restrict__ bih, const float* __restrict__ bhh,
    float* __restrict__ out) {
  __shared__ short hbuf[3][16 * Hn];
  const int w = threadIdx.x >> 6;
  const int lane = threadIdx.x & 63;
  const int quad = lane >> 4;
  const int c = lane & 15;
  const int waveg = blockIdx.x * 3 + w;
  const int rowbase = waveg * 16;

  const f32x4* Wih4 = reinterpret_cast<const f32x4*>(Wih);
  const f32x4* Whh4 = reinterpret_cast<const f32x4*>(Whh);
  s16x8 Bih[6], Bhh[6];
#pragma unroll
  for (int g = 0; g < 6; g++) {
    const int row = g * 16 + c;
    const int v4 = row * (Hn / 4) + quad * 2;
    f32x4 wa = Wih4[v4], wb = Wih4[v4 + 1];
    f32x4 ha = Whh4[v4], hb = Whh4[v4 + 1];
#pragma unroll
    for (int j = 0; j < 4; j++) {
      Bih[g][j] = f2bfs(wa[j]);
      Bih[g][j + 4] = f2bfs(wb[j]);
      Bhh[g][j] = f2bfs(ha[j]);
      Bhh[g][j + 4] = f2bfs(hb[j]);
    }
  }
  const f32x4* Wg4 = reinterpret_cast<const f32x4*>(Wg);
  const f32x4* bg4 = reinterpret_cast<const f32x4*>(bg);
  f32x4 wga = Wg4[quad * 2], wgb = Wg4[quad * 2 + 1];
  f32x4 bga = bg4[quad * 2], bgb = bg4[quad * 2 + 1];
  float wgv[8], bgv[8];
#pragma unroll
  for (int j = 0; j < 4; j++) {
    wgv[j] = wga[j]; wgv[j + 4] = wgb[j];
    bgv[j] = bga[j]; bgv[j + 4] = bgb[j];
  }
  float bihv[6], bhhv[6];
#pragma unroll
  for (int g = 0; g < 6; g++) {
    bihv[g] = bih[g * 16 + c];
    bhhv[g] = bhh[g * 16 + c];
  }

  f32x4 hc0 = {0.f, 0.f, 0.f, 0.f};
  f32x4 hc1 = {0.f, 0.f, 0.f, 0.f};
  s16x8 hfrag = {0, 0, 0, 0, 0, 0, 0, 0};
  const f32x4 z4 = {0.f, 0.f, 0.f, 0.f};

  for (int t = 0; t < T_SNAP; t++) {
    const float top = tops[t * (EQn * 3) + rowbase + c];
    s16x8 xf;
#pragma unroll
    for (int j = 0; j < 8; j++) {
      float x = top * wgv[j] + bgv[j];
      x = x > 0.f ? x : 0.f;
      xf[j] = f2bfs(x);
    }
    f32x4 gi[6], gh[6];
#pragma unroll
    for (int g = 0; g < 6; g++) {
      gi[g] = __builtin_amdgcn_mfma_f32_16x16x32_bf16(xf, Bih[g], z4, 0, 0, 0);
      gh[g] = __builtin_amdgcn_mfma_f32_16x16x32_bf16(hfrag, Bhh[g], z4, 0, 0, 0);
    }
#pragma unroll
    for (int r = 0; r < 4; r++) {
      float rA = sigm(gi[0][r] + bihv[0] + gh[0][r] + bhhv[0]);
      float zA = sigm(gi[2][r] + bihv[2] + gh[2][r] + bhhv[2]);
      float nA = tanhfast(gi[4][r] + bihv[4] + rA * (gh[4][r] + bhhv[4]));
      hc0[r] = (1.f - zA) * nA + zA * hc0[r];
      float rB = sigm(gi[1][r] + bihv[1] + gh[1][r] + bhhv[1]);
      float zB = sigm(gi[3][r] + bihv[3] + gh[3][r] + bhhv[3]);
      float nB = tanhfast(gi[5][r] + bihv[5] + rB * (gh[5][r] + bhhv[5]));
      hc1[r] = (1.f - zB) * nB + zB * hc1[r];
    }
    if (t < T_SNAP - 1) {
      tfb();
#pragma unroll
      for (int r = 0; r < 4; r++) {
        const int row = quad * 4 + r;
        hbuf[w][row * Hn + c] = f2bfs(hc0[r]);
        hbuf[w][row * Hn + 16 + c] = f2bfs(hc1[r]);
      }
      tfb();
      hfrag = *reinterpret_cast<const s16x8*>(&hbuf[w][c * Hn + quad * 8]);
    }
  }
#pragma unroll
  for (int r = 0; r < 4; r++) {
    const int grow = rowbase + quad * 4 + r;
    out[grow * Hn + c] = hc0[r];
    out[grow * Hn + 16 + c] = hc1[r];
  }
}

// ---------------------------------------------------------------------------
extern "C" void kernel_launch(void* const* d_in, const int* in_sizes, int n_in,
                              void* d_out, int out_size, void* d_ws, size_t ws_size,
                              hipStream_t stream) {
  const int* ei = (const int*)d_in[0];
  const float* Wg = (const float*)d_in[1];
  const float* bg = (const float*)d_in[2];
  const float* Wih = (const float*)d_in[3];
  const float* Whh = (const float*)d_in[4];
  const float* bih = (const float*)d_in[5];
  const float* bhh = (const float*)d_in[6];

  unsigned char* ws = (unsigned char*)d_ws;
  unsigned* rp = (unsigned*)ws;                                      // [T][N+1] u32
  unsigned* csr = (unsigned*)(ws + (size_t)T_SNAP * (Nn + 1) * 4);   // [T][EQ]  u32
  float* tops = (float*)(ws + (size_t)T_SNAP * (Nn + 1) * 4
                            + (size_t)T_SNAP * EQn * 4);             // [T][EQ*3] f32

  csr_build<<<T_SNAP, 1024, 0, stream>>>(ei, rp, csr);
  reach_topk<<<(T_SNAP * EQn) / 4, 256, 0, stream>>>(ei, rp, csr, tops);
  gru_kernel<<<256, 192, 0, stream>>>(tops, Wg, bg, Wih, Whh, bih, bhh,
                                      (float*)d_out);
}